// Round 1
// baseline (97.221 us; speedup 1.0000x reference)
//
#include <hip/hip_runtime.h>
#include <hip/hip_bf16.h>

// PatchExtractor3d: out[b, c*27 + i*9 + j*3 + l, d, h, w] = x_pad[b, c, d+i-1, h+j-1, w+l-1]
// x: (2, 3, 32, 128, 128) f32 ; out: (2, 81, 32, 128, 128) f32
// Memory-bound: 340 MB writes, 12.6 MB input (L2/L3-resident, 27x reuse).

#define B_  2
#define C_  3
#define D_  32
#define H_  128
#define W_  128

__global__ __launch_bounds__(256) void patch3d_kernel(const float* __restrict__ x,
                                                      float* __restrict__ out) {
    // blockIdx.y = b*81 + co  (162 values) -- all uniform per block -> scalar ops
    const int bc = blockIdx.y;
    const int b  = bc / 81;
    const int co = bc - b * 81;
    const int c  = co / 27;
    const int r  = co - c * 27;
    const int i  = r / 9;
    const int r2 = r - i * 9;
    const int j  = r2 / 3;
    const int l  = r2 - j * 3;

    // tid enumerates (d, h, w4): 32 * 128 * 32 = 131072 float4s per (b,co)
    const int tid = blockIdx.x * 256 + threadIdx.x;
    const int w4  = tid & 31;          // float4 index within W row (W/4 = 32)
    const int h   = (tid >> 5) & 127;
    const int d   = tid >> 12;         // 0..31

    const int dp = d + i - 1;          // source depth
    const int hp = h + j - 1;          // source height

    float4 v = make_float4(0.f, 0.f, 0.f, 0.f);
    if ((unsigned)dp < (unsigned)D_ && (unsigned)hp < (unsigned)H_) {
        const float* __restrict__ src =
            x + (((size_t)(b * C_ + c) * D_ + dp) * H_ + hp) * W_;
        const int w0 = w4 * 4 + l - 1; // first source w (shift by l-1)
        float t0 = ((unsigned)(w0 + 0) < (unsigned)W_) ? src[w0 + 0] : 0.f;
        float t1 = ((unsigned)(w0 + 1) < (unsigned)W_) ? src[w0 + 1] : 0.f;
        float t2 = ((unsigned)(w0 + 2) < (unsigned)W_) ? src[w0 + 2] : 0.f;
        float t3 = ((unsigned)(w0 + 3) < (unsigned)W_) ? src[w0 + 3] : 0.f;
        v = make_float4(t0, t1, t2, t3);
    }

    // out flat offset: (((b*81+co)*D + d)*H + h)*W + w  ==  bc*524288 + tid*4
    float* dst = out + (size_t)bc * (D_ * H_ * W_) + (size_t)tid * 4;
    *reinterpret_cast<float4*>(dst) = v;
}

extern "C" void kernel_launch(void* const* d_in, const int* in_sizes, int n_in,
                              void* d_out, int out_size, void* d_ws, size_t ws_size,
                              hipStream_t stream) {
    const float* x = (const float*)d_in[0];
    float* out = (float*)d_out;

    // 131072 float4s per (b,co) -> 512 blocks of 256 threads; 162 (b,co) pairs
    dim3 grid(512, B_ * 81, 1);
    dim3 block(256, 1, 1);
    patch3d_kernel<<<grid, block, 0, stream>>>(x, out);
}

// Round 2
// 72.759 us; speedup vs baseline: 1.3362x; 1.3362x over previous
//
#include <hip/hip_runtime.h>
#include <hip/hip_bf16.h>

// PatchExtractor3d: out[b, c*27 + i*9 + j*3 + l, d, h, w] = x_pad[b, c, d+i-1, h+j-1, w+l-1]
// x: (2, 3, 32, 128, 128) f32 ; out: (2, 81, 32, 128, 128) f32 (339.7 MB)
//
// Structure: one thread per (b,c,d,h,w4) source float4 position; produces all
// 27 (i,j,l) output variants. 9 aligned unconditional float4 row loads (OOB
// rows -> zeros), w-edge elements via lane shuffle (lane-group boundary
// coincides with the w-pad-zero case), 27 back-to-back float4 stores.
// VMEM per 16B output: 1.33 vs 5 in the naive version.

#define B_  2
#define C_  3
#define D_  32
#define H_  128
#define W_  128
#define CHW ((size_t)(D_ * H_ * W_))   // 524288 floats per output channel

__global__ __launch_bounds__(256) void patch3d_kernel(const float* __restrict__ x,
                                                      float* __restrict__ out) {
    const int bc  = blockIdx.y;                 // b*3 + c, 0..5 (block-uniform)
    const int tid = blockIdx.x * 256 + threadIdx.x;
    const int w4  = tid & 31;                   // float4 index in W (W/4 = 32)
    const int h   = (tid >> 5) & 127;
    const int d   = tid >> 12;                  // block-uniform (4096 tids per d)

    const float* __restrict__ src = x + (size_t)bc * CHW;
    // out flat = (bc*27 + i*9+j*3+l)*CHW + d*16384 + h*128 + w4*4; spatial part == tid*4
    float* __restrict__ dst = out + (size_t)bc * 27 * CHW + (size_t)tid * 4;

    float4 v[3][3];
    float  le[3][3], ri[3][3];

#pragma unroll
    for (int i = 0; i < 3; ++i) {
        const int dp = d + i - 1;
#pragma unroll
        for (int j = 0; j < 3; ++j) {
            const int hp = h + j - 1;
            float4 t = make_float4(0.f, 0.f, 0.f, 0.f);
            if (((unsigned)dp < (unsigned)D_) & ((unsigned)hp < (unsigned)H_)) {
                t = *reinterpret_cast<const float4*>(src + ((size_t)dp * H_ + hp) * W_ + w4 * 4);
            }
            // left  = src[..., w4*4 - 1]  (0 when w4==0: that's the pad element)
            // right = src[..., w4*4 + 4]  (0 when w4==31)
            // lanes 0..31 and 32..63 are different h rows, but the cross-group
            // shuffle leak lands exactly on the masked w4==0 / w4==31 lanes.
            float l_ = __shfl_up(t.w, 1, 64);
            float r_ = __shfl_down(t.x, 1, 64);
            if (w4 == 0)  l_ = 0.f;
            if (w4 == 31) r_ = 0.f;
            v[i][j] = t;  le[i][j] = l_;  ri[i][j] = r_;
        }
    }

#pragma unroll
    for (int i = 0; i < 3; ++i) {
#pragma unroll
        for (int j = 0; j < 3; ++j) {
            const float4 t = v[i][j];
            const float4 o0 = make_float4(le[i][j], t.x, t.y, t.z);  // l=0: shift left by 1
            const float4 o2 = make_float4(t.y, t.z, t.w, ri[i][j]);  // l=2: shift right by 1
            float* p = dst + (size_t)(i * 9 + j * 3) * CHW;
            *reinterpret_cast<float4*>(p)            = o0;
            *reinterpret_cast<float4*>(p + CHW)      = t;            // l=1: aligned copy
            *reinterpret_cast<float4*>(p + 2 * CHW)  = o2;
        }
    }
}

extern "C" void kernel_launch(void* const* d_in, const int* in_sizes, int n_in,
                              void* d_out, int out_size, void* d_ws, size_t ws_size,
                              hipStream_t stream) {
    const float* x = (const float*)d_in[0];
    float* out = (float*)d_out;

    // x: 131072 float4s per (b,c) volume -> 512 blocks of 256 threads; 6 (b,c) pairs
    dim3 grid(512, B_ * C_, 1);
    dim3 block(256, 1, 1);
    patch3d_kernel<<<grid, block, 0, stream>>>(x, out);
}

// Round 3
// 66.579 us; speedup vs baseline: 1.4602x; 1.0928x over previous
//
#include <hip/hip_runtime.h>
#include <hip/hip_bf16.h>

// PatchExtractor3d: out[b, c*27 + i*9 + j*3 + l, d, h, w] = x_pad[b, c, d+i-1, h+j-1, w+l-1]
// x: (2, 3, 32, 128, 128) f32 ; out: (2, 81, 32, 128, 128) f32 (339.7 MB written)
//
// R2 structure: each thread owns 4 output rows (h = h0 + 2k, k=0..3; wave lane
// bit5 = h-parity), so per channel the wave issues 4 consecutive dwordx4 stores
// covering a contiguous 4KB burst (k*1024B fits the 13-bit store immediate ->
// one address reg per channel). Block covers 32 consecutive h rows -> 16KB
// contiguous per channel per block. 9 row-loads per d-plane are reused across
// the (j,k) overlap: 27 loads + 54 shuffles per 108 stores per thread.

#define B_  2
#define C_  3
#define D_  32
#define H_  128
#define W_  128
#define CHW ((size_t)(D_ * H_ * W_))   // 524288 floats per output channel

__global__ __launch_bounds__(256) void patch3d_kernel(const float* __restrict__ x,
                                                      float* __restrict__ out) {
    const int bc = blockIdx.y;                  // b*3 + c (block-uniform)
    const int t  = blockIdx.x * 256 + threadIdx.x;

    const int w4   = t & 31;                    // float4 index in W (32)
    const int hpar = (t >> 5) & 1;              // h parity (lane bit 5)
    const int hsup = (t >> 6) & 15;             // 8-row supergroup
    const int d    = t >> 10;                   // 0..31 (block-uniform)

    const int h0       = hsup * 8 + hpar;       // first output row; rows h0+2k, k=0..3
    const int base_row = h0 - 1;                // source rows R[m] = base_row + m, m=0..8

    const float* __restrict__ src = x + (size_t)bc * CHW;
    float* __restrict__ dstc = out + (size_t)bc * 27 * CHW
                                   + (size_t)d * (H_ * W_) + (size_t)h0 * W_ + w4 * 4;

#pragma unroll
    for (int i = 0; i < 3; ++i) {
        const int dp = d + i - 1;

        float4 R[9]; float le[9], ri[9];
#pragma unroll
        for (int m = 0; m < 9; ++m) {
            const int hp = base_row + m;
            float4 v = make_float4(0.f, 0.f, 0.f, 0.f);
            if (((unsigned)dp < (unsigned)D_) & ((unsigned)hp < (unsigned)H_)) {
                v = *reinterpret_cast<const float4*>(src + ((size_t)dp * H_ + hp) * W_ + w4 * 4);
            }
            // w-edges from neighbor lanes; cross-parity leak lands exactly on
            // the masked w4==0 / w4==31 lanes (pad-zero positions).
            float l_ = __shfl_up(v.w, 1, 64);
            float r_ = __shfl_down(v.x, 1, 64);
            if (w4 == 0)  l_ = 0.f;
            if (w4 == 31) r_ = 0.f;
            R[m] = v; le[m] = l_; ri[m] = r_;
        }

#pragma unroll
        for (int j = 0; j < 3; ++j) {
#pragma unroll
            for (int l = 0; l < 3; ++l) {
                float* p = dstc + (size_t)(i * 9 + j * 3 + l) * CHW;
#pragma unroll
                for (int k = 0; k < 4; ++k) {
                    const int m = 2 * k + j;           // source row for output h0+2k
                    const float4 v = R[m];
                    float4 o;
                    if (l == 0)      o = make_float4(le[m], v.x, v.y, v.z);
                    else if (l == 1) o = v;
                    else             o = make_float4(v.y, v.z, v.w, ri[m]);
                    // k*256 floats = 1024B: folds into the store immediate
                    *reinterpret_cast<float4*>(p + k * 256) = o;
                }
            }
        }
    }
}

extern "C" void kernel_launch(void* const* d_in, const int* in_sizes, int n_in,
                              void* d_out, int out_size, void* d_ws, size_t ws_size,
                              hipStream_t stream) {
    const float* x = (const float*)d_in[0];
    float* out = (float*)d_out;

    // per (b,c): 32(w4) x 2(hpar) x 16(hsup) x 32(d) = 32768 threads = 128 blocks
    dim3 grid(128, B_ * C_, 1);
    dim3 block(256, 1, 1);
    patch3d_kernel<<<grid, block, 0, stream>>>(x, out);
}